// Round 6
// baseline (559.217 us; speedup 1.0000x reference)
//
#include <hip/hip_runtime.h>

#define NUM_CN   25000
#define NUM_VN   50000
#define NUM_E    200000
#define D_EMBED  16
#define D_HIDDEN 32
#define D_MSG    16
#define BATCH    16

// ---------------------------------------------------------------------------
// Workspace layout (int units) — same 54.41 MB footprint proven in R2-R5:
#define WS_IDS_X   0           // 200000  (FROM node ids, CSR order)
#define WS_IDS_Z   200000      // 200000
#define WS_OFF_X   400000      // 50001
#define WS_OFF_Z   450001      // 50001
#define WS_CNT_X   500002      // 50000
#define WS_CNT_Z   550002      // 50000
#define WS_CUR_X   600002      // 50000
#define WS_CUR_Z   650002      // 50000
#define WS_BITS_X  700002      // 25000 (lives in old incl region, now free)
#define WS_BITS_Z  725002      // 25000
#define WS_A1X     802816      // 6400000 ints = 25.6 MB bf16
#define WS_A1Z     7202816     // 6400000

#define E_BLOCKS   782         // ceil(200000/256)
#define CN_BLOCKS  98          // ceil(25000/256)

// ---------------------------------------------------------------------------
// hist (edge range) + syndrome bit-pack (cn range) in ONE dispatch.
__global__ __launch_bounds__(256) void histpack_kernel(
    const int* __restrict__ ti_x, const int* __restrict__ ti_z,
    int* __restrict__ cnt_x, int* __restrict__ cnt_z,
    const int* __restrict__ syn_x, const int* __restrict__ syn_z,
    unsigned* __restrict__ bits_x, unsigned* __restrict__ bits_z)
{
    if (blockIdx.x < E_BLOCKS) {
        int e = blockIdx.x * 256 + threadIdx.x;
        if (e >= NUM_E) return;
        atomicAdd(&cnt_x[ti_x[e]], 1);
        atomicAdd(&cnt_z[ti_z[e]], 1);
    } else {
        int cn = (blockIdx.x - E_BLOCKS) * 256 + threadIdx.x;
        if (cn >= NUM_CN) return;
        unsigned wx = 0, wz = 0;
#pragma unroll
        for (int b = 0; b < BATCH; ++b) {
            wx |= (unsigned)(syn_x[b * NUM_CN + cn] & 1) << b;
            wz |= (unsigned)(syn_z[b * NUM_CN + cn] & 1) << b;
        }
        bits_x[cn] = wx;
        bits_z[cn] = wz;
    }
}

// Single-kernel scan: one block per channel; thread t owns 49 contiguous
// elements (49*1024 >= 50000). Pass 1: local sum. LDS inclusive scan over
// thread sums. Pass 2: write cur[i] (exclusive) and off[i+1] (inclusive).
__global__ __launch_bounds__(1024) void scan_kernel(
    const int* __restrict__ cnt_x, const int* __restrict__ cnt_z,
    int* __restrict__ off_x, int* __restrict__ off_z,
    int* __restrict__ cur_x, int* __restrict__ cur_z)
{
    __shared__ int sh[1024];
    const int ch = blockIdx.x;
    const int t  = threadIdx.x;
    const int* cnt = ch ? cnt_z : cnt_x;
    int*       off = ch ? off_z : off_x;
    int*       cur = ch ? cur_z : cur_x;

    const int base_i = t * 49;
    int s = 0;
    for (int i = 0; i < 49; ++i) {
        int idx = base_i + i;
        if (idx < NUM_VN) s += cnt[idx];
    }
    sh[t] = s;
    __syncthreads();
#pragma unroll
    for (int d = 1; d < 1024; d <<= 1) {
        int x = 0;
        if (t >= d) x = sh[t - d];
        __syncthreads();
        if (t >= d) sh[t] += x;
        __syncthreads();
    }
    int run = sh[t] - s;   // exclusive prefix for this thread's chunk
    for (int i = 0; i < 49; ++i) {
        int idx = base_i + i;
        if (idx < NUM_VN) {
            int c = cnt[idx];
            cur[idx] = run;
            run += c;
            off[idx + 1] = run;
        }
    }
    if (t == 0) off[0] = 0;
}

// fill: CSR slot stores the FROM node id directly.
__global__ __launch_bounds__(256) void fill_kernel(
    const int* __restrict__ ti_x, const int* __restrict__ ti_z,
    const int* __restrict__ fi_x, const int* __restrict__ fi_z,
    int* __restrict__ cur_x, int* __restrict__ cur_z,
    int* __restrict__ ids_x, int* __restrict__ ids_z)
{
    int e = blockIdx.x * 256 + threadIdx.x;
    if (e >= NUM_E) return;
    int px = atomicAdd(&cur_x[ti_x[e]], 1);
    ids_x[px] = fi_x[e];
    int pz = atomicAdd(&cur_z[ti_z[e]], 1);
    ids_z[pz] = fi_z[e];
}

// ---------------------------------------------------------------------------
__device__ __forceinline__ unsigned pack_bf16(float a, float b) {
    unsigned ua = __float_as_uint(a); ua += 0x7fff + ((ua >> 16) & 1);
    unsigned ub = __float_as_uint(b); ub += 0x7fff + ((ub >> 16) & 1);
    return (ua >> 16) | (ub & 0xffff0000u);
}

// a1[ch][cn][b][32] = h_from @ W1[0:16,:] in bf16, lane-interleaved
// (per-cn block of 64 uint4; lane b's p-th uint4 at block + p*16 + b).
// SYNDROME MASK FOLDED IN: masked (cn,b) entries are bf16 -inf (0xFF80), so
// downstream relu(a2 + a1) == 0 exactly — no mask logic in the hot loop.
__global__ __launch_bounds__(256) void a1_kernel(
    const float* __restrict__ h_from_x, const float* __restrict__ h_from_z,
    const float* __restrict__ Wx1, const float* __restrict__ Wz1,
    const unsigned* __restrict__ bits_x, const unsigned* __restrict__ bits_z,
    uint4* __restrict__ a1x, uint4* __restrict__ a1z)
{
    int t = blockIdx.x * 256 + threadIdx.x;
    if (t >= NUM_CN * BATCH) return;
    const int ch = blockIdx.y;
    const int b  = t & 15;
    const int cn = t >> 4;
    const float* hsrc = (ch ? h_from_z : h_from_x) + ((size_t)b * NUM_CN + cn) * D_EMBED;
    const float* W1   = ch ? Wz1 : Wx1;
    const unsigned bw = (ch ? bits_z : bits_x)[cn];
    const bool on = ((bw >> b) & 1u) != 0u;
    uint4* dst = (ch ? a1z : a1x) + (size_t)cn * 64;

    float hf[D_EMBED];
#pragma unroll
    for (int i = 0; i < 4; ++i) {
        float4 v = ((const float4*)hsrc)[i];
        hf[4 * i + 0] = v.x; hf[4 * i + 1] = v.y;
        hf[4 * i + 2] = v.z; hf[4 * i + 3] = v.w;
    }
    float a[D_HIDDEN];
#pragma unroll
    for (int j = 0; j < D_HIDDEN; ++j) a[j] = 0.0f;
#pragma unroll
    for (int i = 0; i < D_EMBED; ++i) {
        const float fi = hf[i];
#pragma unroll
        for (int j = 0; j < D_HIDDEN; ++j)
            a[j] = fmaf(fi, W1[i * D_HIDDEN + j], a[j]);
    }
    unsigned u[16];
#pragma unroll
    for (int j = 0; j < 16; ++j) {
        unsigned w = pack_bf16(a[2 * j], a[2 * j + 1]);
        u[j] = on ? w : 0xFF80FF80u;   // bf16 -inf pair when masked
    }
#pragma unroll
    for (int p = 0; p < 4; ++p) {
        uint4 q;
        q.x = u[4 * p + 0]; q.y = u[4 * p + 1];
        q.z = u[4 * p + 2]; q.w = u[4 * p + 3];
        dst[p * 16 + b] = q;
    }
}

// ---------------------------------------------------------------------------
__device__ __forceinline__ void acc_edge(
    float2 hacc[16], const float2 a2[16],
    uint4 q0, uint4 q1, uint4 q2, uint4 q3)
{
    unsigned uu[16] = {q0.x, q0.y, q0.z, q0.w,
                       q1.x, q1.y, q1.z, q1.w,
                       q2.x, q2.y, q2.z, q2.w,
                       q3.x, q3.y, q3.z, q3.w};
#pragma unroll
    for (int p = 0; p < 16; ++p) {
        float lo = __uint_as_float(uu[p] << 16);
        float hi = __uint_as_float(uu[p] & 0xffff0000u);
        hacc[p].x += fmaxf(a2[p].x + lo, 0.0f);   // -inf a1 => +0 exactly
        hacc[p].y += fmaxf(a2[p].y + hi, 0.0f);
    }
}

// One channel: a2 = ht @ W1[16:32]; hacc = sum_e relu(a1[from]+a2) (mask is
// pre-folded into a1 as -inf); m = hacc @ W2 packed to 8 bf16-pair words.
__device__ __forceinline__ void channel_accum(
    const float* __restrict__ h_to_slot, int n, int b,
    const int* __restrict__ off, const int* __restrict__ ids,
    const uint4* __restrict__ a1,
    const float* __restrict__ W1, const float* __restrict__ W2,
    unsigned* __restrict__ um)
{
    float ht[D_EMBED];
#pragma unroll
    for (int i = 0; i < 4; ++i) {
        float4 v = ((const float4*)h_to_slot)[i];
        ht[4 * i + 0] = v.x; ht[4 * i + 1] = v.y;
        ht[4 * i + 2] = v.z; ht[4 * i + 3] = v.w;
    }
    float2 a2[16];
#pragma unroll
    for (int p = 0; p < 16; ++p) { a2[p].x = 0.0f; a2[p].y = 0.0f; }
#pragma unroll
    for (int i = 0; i < D_EMBED; ++i) {
        const float hi = ht[i];
        const float* w = W1 + (D_EMBED + i) * D_HIDDEN;
#pragma unroll
        for (int p = 0; p < 16; ++p) {
            a2[p].x = fmaf(hi, w[2 * p],     a2[p].x);
            a2[p].y = fmaf(hi, w[2 * p + 1], a2[p].y);
        }
    }

    float2 hacc[16];
#pragma unroll
    for (int p = 0; p < 16; ++p) { hacc[p].x = 0.0f; hacc[p].y = 0.0f; }

    const int ks = off[n], ke = off[n + 1];
    int k = ks;
    for (; k + 2 <= ke; k += 2) {           // unroll x2: two edges in flight
        const int f0 = ids[k];
        const int f1 = ids[k + 1];
        const uint4* p0 = a1 + (size_t)f0 * 64 + b;
        const uint4* p1 = a1 + (size_t)f1 * 64 + b;
        uint4 q0 = p0[0], q1 = p0[16], q2 = p0[32], q3 = p0[48];
        uint4 r0 = p1[0], r1 = p1[16], r2 = p1[32], r3 = p1[48];
        acc_edge(hacc, a2, q0, q1, q2, q3);
        acc_edge(hacc, a2, r0, r1, r2, r3);
    }
    if (k < ke) {
        const int f0 = ids[k];
        const uint4* p0 = a1 + (size_t)f0 * 64 + b;
        acc_edge(hacc, a2, p0[0], p0[16], p0[32], p0[48]);
    }

    float m[D_MSG];
#pragma unroll
    for (int j = 0; j < D_MSG; ++j) m[j] = 0.0f;
#pragma unroll
    for (int p = 0; p < 16; ++p) {
        const float h0 = hacc[p].x, h1 = hacc[p].y;
        const float* w0 = W2 + (2 * p) * D_MSG;
        const float* w1 = W2 + (2 * p + 1) * D_MSG;
#pragma unroll
        for (int j = 0; j < D_MSG; ++j)
            m[j] = fmaf(h0, w0[j], fmaf(h1, w1[j], m[j]));
    }
#pragma unroll
    for (int j = 0; j < 8; ++j) um[j] = pack_bf16(m[2 * j], m[2 * j + 1]);
}

// gather: thread=(n,b); writes packed bf16 {mx|mz} (64 B) into the thread's
// OWN final-output slot in d_out (node kernel reads then overwrites it).
__global__ __launch_bounds__(256) void gather_kernel(
    const float* __restrict__ h_to,
    const int* __restrict__ off_x, const int* __restrict__ ids_x,
    const int* __restrict__ off_z, const int* __restrict__ ids_z,
    const uint4* __restrict__ a1x, const uint4* __restrict__ a1z,
    const float* __restrict__ Wx1, const float* __restrict__ Wx2,
    const float* __restrict__ Wz1, const float* __restrict__ Wz2,
    uint4* __restrict__ out_m)
{
    const int t = blockIdx.x * 256 + threadIdx.x;   // grid exactly covers range
    const int b = t & (BATCH - 1);
    const int n = t >> 4;
    const size_t slot = (size_t)b * NUM_VN + n;
    const float* ht_slot = h_to + slot * D_EMBED;

    unsigned um[16];
    channel_accum(ht_slot, n, b, off_x, ids_x, a1x, Wx1, Wx2, um);
    channel_accum(ht_slot, n, b, off_z, ids_z, a1z, Wz1, Wz2, um + 8);

    uint4* dst = out_m + slot * 4;
#pragma unroll
    for (int p = 0; p < 4; ++p) {
        uint4 q;
        q.x = um[4 * p + 0]; q.y = um[4 * p + 1];
        q.z = um[4 * p + 2]; q.w = um[4 * p + 3];
        dst[p] = q;
    }
}

// node MLP: reads own slot {mx|mz} + h_to, 48->32(relu)->16, overwrites slot
// with the final fp32 output. out NOT __restrict__ (deliberate self-alias).
__global__ __launch_bounds__(256) void node_kernel(
    const float* __restrict__ h_to,
    const float* __restrict__ We1, const float* __restrict__ We2,
    float* out)
{
    const int t = blockIdx.x * 256 + threadIdx.x;
    const int b = t & (BATCH - 1);
    const int n = t >> 4;
    const size_t slot = (size_t)b * NUM_VN + n;

    const uint4* pm = (const uint4*)out + slot * 4;
    uint4 q0 = pm[0], q1 = pm[1], q2 = pm[2], q3 = pm[3];
    unsigned uu[16] = {q0.x, q0.y, q0.z, q0.w,
                       q1.x, q1.y, q1.z, q1.w,
                       q2.x, q2.y, q2.z, q2.w,
                       q3.x, q3.y, q3.z, q3.w};
    float f[48];
#pragma unroll
    for (int p = 0; p < 16; ++p) {
        f[2 * p]     = __uint_as_float(uu[p] << 16);
        f[2 * p + 1] = __uint_as_float(uu[p] & 0xffff0000u);
    }
#pragma unroll
    for (int i = 0; i < 4; ++i) {
        float4 v = ((const float4*)(h_to + slot * D_EMBED))[i];
        f[32 + 4 * i + 0] = v.x; f[32 + 4 * i + 1] = v.y;
        f[32 + 4 * i + 2] = v.z; f[32 + 4 * i + 3] = v.w;
    }

    float2 hid[16];
#pragma unroll
    for (int p = 0; p < 16; ++p) { hid[p].x = 0.0f; hid[p].y = 0.0f; }
#pragma unroll
    for (int i = 0; i < 48; ++i) {
        const float fi = f[i];
        const float* w = We1 + i * D_HIDDEN;
#pragma unroll
        for (int p = 0; p < 16; ++p) {
            hid[p].x = fmaf(fi, w[2 * p],     hid[p].x);
            hid[p].y = fmaf(fi, w[2 * p + 1], hid[p].y);
        }
    }
#pragma unroll
    for (int p = 0; p < 16; ++p) {
        hid[p].x = fmaxf(hid[p].x, 0.0f);
        hid[p].y = fmaxf(hid[p].y, 0.0f);
    }

    float o[D_EMBED];
#pragma unroll
    for (int k = 0; k < D_EMBED; ++k) o[k] = 0.0f;
#pragma unroll
    for (int p = 0; p < 16; ++p) {
        const float h0 = hid[p].x, h1 = hid[p].y;
        const float* w0 = We2 + (2 * p) * D_EMBED;
        const float* w1 = We2 + (2 * p + 1) * D_EMBED;
#pragma unroll
        for (int k = 0; k < D_EMBED; ++k)
            o[k] = fmaf(h0, w0[k], fmaf(h1, w1[k], o[k]));
    }

#pragma unroll
    for (int i = 0; i < 4; ++i) {
        float4 v;
        v.x = o[4 * i + 0]; v.y = o[4 * i + 1];
        v.z = o[4 * i + 2]; v.w = o[4 * i + 3];
        ((float4*)(out + slot * D_EMBED))[i] = v;
    }
}

// ---------------------------------------------------------------------------
extern "C" void kernel_launch(void* const* d_in, const int* in_sizes, int n_in,
                              void* d_out, int out_size, void* d_ws, size_t ws_size,
                              hipStream_t stream) {
    const float* h_from_x = (const float*)d_in[0];
    const float* h_from_z = (const float*)d_in[1];
    const float* h_to     = (const float*)d_in[2];
    const int*   syn_x    = (const int*)d_in[3];
    const int*   syn_z    = (const int*)d_in[4];
    const int*   fi_x     = (const int*)d_in[5];
    const int*   ti_x     = (const int*)d_in[6];
    const int*   fi_z     = (const int*)d_in[7];
    const int*   ti_z     = (const int*)d_in[8];
    const float* Wx1      = (const float*)d_in[9];
    const float* Wx2      = (const float*)d_in[10];
    const float* Wz1      = (const float*)d_in[11];
    const float* Wz2      = (const float*)d_in[12];
    const float* We1      = (const float*)d_in[13];
    const float* We2      = (const float*)d_in[14];

    int* ws = (int*)d_ws;
    int*      ids_x  = ws + WS_IDS_X;
    int*      ids_z  = ws + WS_IDS_Z;
    int*      off_x  = ws + WS_OFF_X;
    int*      off_z  = ws + WS_OFF_Z;
    int*      cnt_x  = ws + WS_CNT_X;
    int*      cnt_z  = ws + WS_CNT_Z;
    int*      cur_x  = ws + WS_CUR_X;
    int*      cur_z  = ws + WS_CUR_Z;
    unsigned* bits_x = (unsigned*)(ws + WS_BITS_X);
    unsigned* bits_z = (unsigned*)(ws + WS_BITS_Z);
    uint4*    a1x    = (uint4*)(ws + WS_A1X);
    uint4*    a1z    = (uint4*)(ws + WS_A1Z);

    hipMemsetAsync(cnt_x, 0, 2 * NUM_VN * sizeof(int), stream);

    histpack_kernel<<<dim3(E_BLOCKS + CN_BLOCKS), dim3(256), 0, stream>>>(
        ti_x, ti_z, cnt_x, cnt_z, syn_x, syn_z, bits_x, bits_z);
    scan_kernel<<<dim3(2), dim3(1024), 0, stream>>>(
        cnt_x, cnt_z, off_x, off_z, cur_x, cur_z);
    fill_kernel<<<dim3(E_BLOCKS), dim3(256), 0, stream>>>(
        ti_x, ti_z, fi_x, fi_z, cur_x, cur_z, ids_x, ids_z);
    a1_kernel<<<dim3((NUM_CN * BATCH + 255) / 256, 2), dim3(256), 0, stream>>>(
        h_from_x, h_from_z, Wx1, Wz1, bits_x, bits_z, a1x, a1z);

    gather_kernel<<<dim3((NUM_VN * BATCH) / 256), dim3(256), 0, stream>>>(
        h_to, off_x, ids_x, off_z, ids_z, a1x, a1z,
        Wx1, Wx2, Wz1, Wz2, (uint4*)d_out);

    node_kernel<<<dim3((NUM_VN * BATCH) / 256), dim3(256), 0, stream>>>(
        h_to, We1, We2, (float*)d_out);
}